// Round 4
// baseline (589.034 us; speedup 1.0000x reference)
//
#include <hip/hip_runtime.h>

typedef __attribute__((ext_vector_type(8))) short s16x8;
typedef __attribute__((ext_vector_type(8))) __bf16 bf16x8;
typedef __attribute__((ext_vector_type(4))) float f32x4;

__device__ inline float bf2f(ushort u){ return __uint_as_float(((unsigned)u)<<16); }
__device__ inline ushort f2bf(float f){
  unsigned u = __float_as_uint(f);
  unsigned r = (u + 0x7fffu + ((u>>16)&1u)) >> 16;
  return (ushort)r;
}

__device__ inline void gl_lds16(const ushort* g, ushort* l){
  __builtin_amdgcn_global_load_lds(
      (const __attribute__((address_space(1))) unsigned int*)g,
      (__attribute__((address_space(3))) unsigned int*)l,
      16, 0, 0);
}

// ---------------- CSR build ----------------
__global__ void k_count(const int* __restrict__ ei, int* __restrict__ counts,
                        int E, int ET){
  int e = blockIdx.x*256 + threadIdx.x;
  if (e >= ET) return;
  int dst = (e < E) ? ei[E + e] : (e - E);
  atomicAdd(&counts[dst], 1);
}

__global__ __launch_bounds__(1024) void k_scan(const int* __restrict__ cnt,
                                               int* __restrict__ indptr, int N){
  __shared__ int part[1024];
  int t = threadIdx.x;
  int per = (N + 1023) / 1024;
  int base = t * per;
  int s = 0;
  for (int i = 0; i < per; ++i){ int idx = base + i; if (idx < N) s += cnt[idx]; }
  part[t] = s; __syncthreads();
  for (int off = 1; off < 1024; off <<= 1){
    int v = (t >= off) ? part[t-off] : 0;
    __syncthreads();
    if (t >= off) part[t] += v;
    __syncthreads();
  }
  int run = (t == 0) ? 0 : part[t-1];
  for (int i = 0; i < per; ++i){
    int idx = base + i;
    if (idx < N){ indptr[idx] = run; run += cnt[idx]; }
  }
  if (t == 1023) indptr[N] = run;
}

__global__ void k_fill(const int* __restrict__ ei, const float* __restrict__ ew,
                       const int* __restrict__ indptr, int* __restrict__ cursor,
                       int* __restrict__ csrc, float* __restrict__ cew,
                       int E, int ET){
  int e = blockIdx.x*256 + threadIdx.x;
  if (e >= ET) return;
  int src, dst; float w;
  if (e < E){ src = ei[e]; dst = ei[E + e]; w = ew[e]; }
  else { src = dst = e - E; w = 1.0f; }
  int pos = indptr[dst] + atomicAdd(&cursor[dst], 1);
  csrc[pos] = src; cew[pos] = w;
}

// ---------------- conversions / packing ----------------
__global__ void k_f2b(const float* __restrict__ x, ushort* __restrict__ xb, int n8){
  int i = blockIdx.x*256 + threadIdx.x;
  if (i >= n8) return;
  const float4* p = (const float4*)x + (size_t)i*2;
  float4 a = p[0], b = p[1];
  s16x8 o;
  o[0]=(short)f2bf(a.x); o[1]=(short)f2bf(a.y); o[2]=(short)f2bf(a.z); o[3]=(short)f2bf(a.w);
  o[4]=(short)f2bf(b.x); o[5]=(short)f2bf(b.y); o[6]=(short)f2bf(b.z); o[7]=(short)f2bf(b.w);
  *((s16x8*)xb + i) = o;
}

// BT[n][k] = concat(W, LW)^T, zero-padded to Npad rows. Coalesced via LDS tile.
__global__ __launch_bounds__(256) void k_packB(
    const float* __restrict__ W, const float* __restrict__ LW,
    ushort* __restrict__ BT, int K, int NW, int NL, int Npad)
{
  __shared__ float tile[32][33];
  int k0 = blockIdx.x*32, n0 = blockIdx.y*32;
  int c = threadIdx.x & 31, r4 = threadIdx.x >> 5;
  #pragma unroll
  for (int rr = 0; rr < 32; rr += 8){
    int k = k0 + r4 + rr, n = n0 + c;
    float v = 0.f;
    if (k < K){
      if (n < NW)            v = W[(size_t)k*NW + n];
      else if (n < NW + NL)  v = LW[(size_t)k*NL + (n - NW)];
    }
    tile[r4+rr][c] = v;
  }
  __syncthreads();
  #pragma unroll
  for (int rr = 0; rr < 32; rr += 8){
    int n = n0 + r4 + rr, k = k0 + c;
    if (n < Npad && k < K) BT[(size_t)n*K + k] = f2bf(tile[c][r4+rr]);
  }
}

// ---------------- MFMA GEMM + fused attention-logit epilogue ----------------
// C[Mpad][*] = A[Mpad][K] * BT^T ; cols <GW -> Gatt bf16, [GW,GW+SW) -> Skip bf16
// If als!=nullptr and block cols < GW: atomicAdd per-row partial h·a_s / h·a_d
// (head = col/256) into als/ald (must be pre-zeroed). Rows >= NROW skipped.
__global__ __launch_bounds__(256) void k_gemm(
    const ushort* __restrict__ A, const ushort* __restrict__ BT,
    ushort* __restrict__ Gatt, ushort* __restrict__ Skip,
    float* __restrict__ als, float* __restrict__ ald,
    const float* __restrict__ a_s, const float* __restrict__ a_d,
    int K, int GW, int SW, int NCB, int CPX, int NROW)
{
  __shared__ ushort As[128*64];
  __shared__ ushort Bs[128*64];
  const int bid = blockIdx.x;
  const int lb = CPX ? ((bid & 7)*CPX + (bid >> 3)) : bid;  // XCD-chunked, bijective
  const size_t row0 = (size_t)(lb / NCB) * 128;
  const size_t col0 = (size_t)(lb % NCB) * 128;             // col fastest: A-panel L2 reuse
  const int t = threadIdx.x;
  const int l = t & 63, w = t >> 6;
  const int wr = w >> 1, wc = w & 1;
  // staging: instr i covers rows [i*32+w*8, +8); lane: row sr=l>>3, slot l&7
  const int sr = l >> 3;
  const int sk = ((l & 7) ^ sr) << 3;       // pre-swizzled source k-offset
  const ushort* gA = A  + (row0 + w*8 + sr)*(size_t)K + sk;
  const ushort* gB = BT + (col0 + w*8 + sr)*(size_t)K + sk;
  ushort* lA = As + w*512;                  // wave-uniform linear dest
  ushort* lB = Bs + w*512;
  const int rf = l & 15;
  const int g4 = l >> 4;
  f32x4 acc[4][4] = {};

  for (int k0 = 0; k0 < K; k0 += 64){
    #pragma unroll
    for (int i = 0; i < 4; ++i){
      gl_lds16(gA + k0 + (size_t)(i*32)*K, lA + i*2048);
      gl_lds16(gB + k0 + (size_t)(i*32)*K, lB + i*2048);
    }
    __syncthreads();
    #pragma unroll
    for (int kk = 0; kk < 2; ++kk){
      const int koff = ((((kk<<2) | g4) ^ (rf & 7)) << 3);  // swizzled read
      bf16x8 af[4], bfr[4];
      #pragma unroll
      for (int i = 0; i < 4; ++i)
        af[i] = __builtin_bit_cast(bf16x8, *(const s16x8*)(As + (wr*64 + i*16 + rf)*64 + koff));
      #pragma unroll
      for (int j = 0; j < 4; ++j)
        bfr[j] = __builtin_bit_cast(bf16x8, *(const s16x8*)(Bs + (wc*64 + j*16 + rf)*64 + koff));
      #pragma unroll
      for (int i = 0; i < 4; ++i)
        #pragma unroll
        for (int j = 0; j < 4; ++j)
          acc[i][j] = __builtin_amdgcn_mfma_f32_16x16x32_bf16(af[i], bfr[j], acc[i][j], 0, 0, 0);
    }
    __syncthreads();
  }

  // C write
  #pragma unroll
  for (int i = 0; i < 4; ++i){
    #pragma unroll
    for (int j = 0; j < 4; ++j){
      int gc = (int)col0 + wc*64 + j*16 + rf;
      #pragma unroll
      for (int r = 0; r < 4; ++r){
        size_t gr = row0 + wr*64 + i*16 + (g4<<2) + r;
        float v = acc[i][j][r];
        if (gc < GW)            Gatt[gr*GW + gc] = f2bf(v);
        else if (gc < GW + SW)  Skip[gr*SW + (gc - GW)] = f2bf(v);
      }
    }
  }

  // fused attention logits (layers 1-2; head width 256, 4 heads)
  if (als && (int)col0 < GW){
    const int hcol = (int)col0 + wc*64;         // wave col base (within one head)
    const int head = hcol >> 8;
    const float* pas = a_s + (head << 8) + (hcol & 255);
    const float* pad_ = a_d + (head << 8) + (hcol & 255);
    float as4[4], ad4[4];
    #pragma unroll
    for (int j = 0; j < 4; ++j){ as4[j] = pas[j*16 + rf]; ad4[j] = pad_[j*16 + rf]; }
    #pragma unroll
    for (int i = 0; i < 4; ++i){
      #pragma unroll
      for (int r = 0; r < 4; ++r){
        float vs = 0.f, vd = 0.f;
        #pragma unroll
        for (int j = 0; j < 4; ++j){
          float v = acc[i][j][r];
          vs += v * as4[j]; vd += v * ad4[j];
        }
        #pragma unroll
        for (int o = 1; o < 16; o <<= 1){
          vs += __shfl_xor(vs, o);
          vd += __shfl_xor(vd, o);
        }
        size_t gr = row0 + wr*64 + i*16 + (g4<<2) + r;
        if (rf == 0 && gr < (size_t)NROW){
          atomicAdd(&als[gr*4 + head], vs);
          atomicAdd(&ald[gr*4 + head], vd);
        }
      }
    }
  }
}

// ---------------- softmax + aggregate + bias + skip + ELU (layers 1-2) ----------------
__global__ __launch_bounds__(256) void k_agg(
    const ushort* __restrict__ Gatt,   // [Mpad][1024] bf16
    const ushort* __restrict__ Skip,   // [Mpad][1024] bf16
    const float*  __restrict__ als,    // [N][4]
    const float*  __restrict__ ald,    // [N][4]
    const float*  __restrict__ bias,   // [1024]
    const float*  __restrict__ lbias,  // [1024]
    const int*    __restrict__ indptr,
    const int*    __restrict__ csrc,
    const float*  __restrict__ cew,
    ushort* __restrict__ Hout,         // [Mpad][1024] bf16
    int N)
{
  const int n = blockIdx.x;
  const int t = threadIdx.x;
  const int l = t & 63, w = t >> 6;
  const int beg = indptr[n];
  const int deg = indptr[n+1] - beg;
  __shared__ float s_ald[4], s_m[4], s_den[4];
  __shared__ int   s_src[64];
  __shared__ float s_w[64][4];
  __shared__ float s_part[3][64][16];
  if (t < 4) s_ald[t] = ald[(size_t)n*4 + t];
  __syncthreads();
  const bool fast = (deg <= 64);

  if (fast){
    // one staged pass: raw logits -> wave-reduce max+den -> normalized weights
    int e2 = t >> 2, hh = t & 3;
    if (e2 < deg){
      int s = csrc[beg + e2];
      if (hh == 0) s_src[e2] = s;
      float r_ = als[(size_t)s*4 + hh] + s_ald[hh];
      s_w[e2][hh] = r_ > 0.f ? r_ : 0.2f*r_;
    }
    __syncthreads();
    float mye = (l < deg) ? s_w[l][w] : -1e30f;
    float mx = mye;
    #pragma unroll
    for (int o = 32; o; o >>= 1) mx = fmaxf(mx, __shfl_xor(mx, o));
    float ex = (l < deg) ? __expf(mye - mx) : 0.f;
    float den = ex;
    #pragma unroll
    for (int o = 32; o; o >>= 1) den += __shfl_xor(den, o);
    den += 1e-16f;
    if (l < deg) s_w[l][w] = ex / den * cew[beg + l];
    __syncthreads();
  } else {
    const float aldh = s_ald[w];
    float mx = -1e30f;
    for (int i = l; i < deg; i += 64){
      int s = csrc[beg+i];
      float e = als[(size_t)s*4 + w] + aldh;
      e = e > 0.f ? e : 0.2f*e;
      mx = fmaxf(mx, e);
    }
    #pragma unroll
    for (int off = 32; off; off >>= 1) mx = fmaxf(mx, __shfl_xor(mx, off));
    if (l == 0) s_m[w] = mx;
    __syncthreads();
    const float mh = s_m[w];
    float den = 0.f;
    for (int i = l; i < deg; i += 64){
      int s = csrc[beg+i];
      float e = als[(size_t)s*4 + w] + aldh;
      e = e > 0.f ? e : 0.2f*e;
      den += __expf(e - mh);
    }
    #pragma unroll
    for (int off = 32; off; off >>= 1) den += __shfl_xor(den, off);
    if (l == 0) s_den[w] = den + 1e-16f;
    __syncthreads();
  }

  // gather: 4 wave-groups, each every 4th edge; thread owns 16 cols
  const int h2 = l >> 4;                // head of cols l*16..l*16+15
  const ushort* gbase = Gatt + (size_t)l*16;
  float a[16];
  #pragma unroll
  for (int q = 0; q < 16; ++q) a[q] = 0.f;
  for (int c0 = 0; c0 < deg; c0 += 64){
    int nc = min(64, deg - c0);
    if (!fast){
      int ei2 = t >> 2, hh = t & 3;
      if (ei2 < nc){
        int s = csrc[beg + c0 + ei2];
        if (hh == 0) s_src[ei2] = s;
        float e = als[(size_t)s*4 + hh] + s_ald[hh];
        e = e > 0.f ? e : 0.2f*e;
        s_w[ei2][hh] = __expf(e - s_m[hh]) / s_den[hh] * cew[beg + c0 + ei2];
      }
      __syncthreads();
    }
    for (int j = w; j < nc; j += 4){
      int s = s_src[j];
      float wg = s_w[j][h2];
      const ushort* rp = gbase + (size_t)s*1024;
      s16x8 h0 = *(const s16x8*)rp;
      s16x8 h1 = *(const s16x8*)(rp + 8);
      #pragma unroll
      for (int q = 0; q < 8; ++q) a[q] += wg * bf2f((ushort)h0[q]);
      #pragma unroll
      for (int q = 0; q < 8; ++q) a[q+8] += wg * bf2f((ushort)h1[q]);
    }
    __syncthreads();
  }
  if (w){
    #pragma unroll
    for (int q = 0; q < 16; ++q) s_part[w-1][l][q] = a[q];
  }
  __syncthreads();
  if (w == 0){
    #pragma unroll
    for (int q = 0; q < 16; ++q) a[q] += s_part[0][l][q] + s_part[1][l][q] + s_part[2][l][q];
    const int col = l*16;
    s16x8 sk0 = *(const s16x8*)(Skip + (size_t)n*1024 + col);
    s16x8 sk1 = *(const s16x8*)(Skip + (size_t)n*1024 + col + 8);
    s16x8 ov0, ov1;
    #pragma unroll
    for (int q = 0; q < 8; ++q){
      float v = a[q] + bias[col+q] + lbias[col+q] + bf2f((ushort)sk0[q]);
      v = v > 0.f ? v : __expf(v) - 1.f;
      ov0[q] = (short)f2bf(v);
      float v2 = a[q+8] + bias[col+8+q] + lbias[col+8+q] + bf2f((ushort)sk1[q]);
      v2 = v2 > 0.f ? v2 : __expf(v2) - 1.f;
      ov1[q] = (short)f2bf(v2);
    }
    *(s16x8*)(Hout + (size_t)n*1024 + col)     = ov0;
    *(s16x8*)(Hout + (size_t)n*1024 + col + 8) = ov1;
  }
}

// ---------------- layer 3: logits (H=6, C=10) ----------------
__global__ void k_al3(const ushort* __restrict__ G3, const float* __restrict__ a_s,
                      const float* __restrict__ a_d,
                      float* __restrict__ als, float* __restrict__ ald, int N){
  int n = blockIdx.x*256 + threadIdx.x;
  if (n >= N) return;
  const ushort* row = G3 + (size_t)n*60;
  #pragma unroll
  for (int h = 0; h < 6; ++h){
    float ps = 0.f, pd = 0.f;
    #pragma unroll
    for (int c = 0; c < 10; ++c){
      float v = bf2f(row[h*10 + c]);
      ps += v * a_s[h*10 + c];
      pd += v * a_d[h*10 + c];
    }
    als[(size_t)n*6 + h] = ps;
    ald[(size_t)n*6 + h] = pd;
  }
}

// ---------------- layer 3: edge-parallel online softmax + aggregate + mean ----------------
__global__ __launch_bounds__(64) void k_agg3(
    const ushort* __restrict__ G3,     // [Mpad][60] bf16
    const ushort* __restrict__ Skip3,  // [Mpad][10] bf16
    const float*  __restrict__ als,    // [N][6]
    const float*  __restrict__ ald,    // [N][6]
    const float*  __restrict__ b3,     // [10]
    const float*  __restrict__ lb3,    // [10]
    const int*    __restrict__ indptr,
    const int*    __restrict__ csrc,
    const float*  __restrict__ cew,
    float* __restrict__ out, int N)
{
  const int n = blockIdx.x;
  const int l = threadIdx.x;
  const int beg = indptr[n], deg = indptr[n+1] - beg;
  __shared__ float s_aldh[6];
  __shared__ int   s_src[64];
  __shared__ float s_wgt[64][6];
  __shared__ float s_o[6][10];
  if (l < 6) s_aldh[l] = ald[(size_t)n*6 + l];
  __syncthreads();
  float m0=-1e30f,m1=-1e30f,m2=-1e30f,m3=-1e30f,m4=-1e30f,m5=-1e30f;
  float d0=0.f,d1=0.f,d2=0.f,d3=0.f,d4=0.f,d5=0.f;
  for (int c0 = 0; c0 < deg; c0 += 64){
    int nc = min(64, deg - c0);
    bool act = l < nc;
    int s = act ? csrc[beg + c0 + l] : 0;
#define HP(hh, mm, dd) { \
    float e = -1e30f; \
    if (act){ float r_ = als[(size_t)s*6 + hh] + s_aldh[hh]; e = r_ > 0.f ? r_ : 0.2f*r_; } \
    float cm = e; \
    for (int o_ = 32; o_; o_ >>= 1) cm = fmaxf(cm, __shfl_xor(cm, o_)); \
    float nm = fmaxf(mm, cm); \
    float ex = act ? __expf(e - nm) : 0.f; \
    for (int o_ = 32; o_; o_ >>= 1) ex += __shfl_xor(ex, o_); \
    dd = dd * __expf(mm - nm) + ex; mm = nm; }
    HP(0,m0,d0) HP(1,m1,d1) HP(2,m2,d2) HP(3,m3,d3) HP(4,m4,d4) HP(5,m5,d5)
#undef HP
  }
  const int h = l / 10, c = l % 10;     // valid for l<60
  float o = 0.f;
  for (int c0 = 0; c0 < deg; c0 += 64){
    int nc = min(64, deg - c0);
    if (l < nc){
      int s = csrc[beg + c0 + l];
      s_src[l] = s;
      float w_ = cew[beg + c0 + l];
#define WP(hh, mm, dd) { \
      float r_ = als[(size_t)s*6 + hh] + s_aldh[hh]; \
      float e = r_ > 0.f ? r_ : 0.2f*r_; \
      s_wgt[l][hh] = __expf(e - mm) / (dd + 1e-16f) * w_; }
      WP(0,m0,d0) WP(1,m1,d1) WP(2,m2,d2) WP(3,m3,d3) WP(4,m4,d4) WP(5,m5,d5)
#undef WP
    }
    __syncthreads();
    if (l < 60){
      for (int i = 0; i < nc; ++i)
        o += s_wgt[i][h] * bf2f(G3[(size_t)s_src[i]*60 + l]);
    }
    __syncthreads();
  }
  if (l < 60) s_o[h][c] = o;
  __syncthreads();
  if (l < 10){
    float v = (s_o[0][l]+s_o[1][l]+s_o[2][l]+s_o[3][l]+s_o[4][l]+s_o[5][l]) * (1.0f/6.0f);
    v += b3[l] + lb3[l] + bf2f(Skip3[(size_t)n*10 + l]);
    out[(size_t)n*10 + l] = v;
  }
}

// ---------------- host ----------------
extern "C" void kernel_launch(void* const* d_in, const int* in_sizes, int n_in,
                              void* d_out, int out_size, void* d_ws, size_t ws_size,
                              hipStream_t stream)
{
  const int N = 20000, F = 128, E = 320000, ET = E + N;
  const int Mpad = 20096;            // 157 * 128
  const int F1 = 1024, NT = 2048;
  const int NWG = (Mpad/128)*(NT/128);   // 2512, % 8 == 0

  const float* x   = (const float*)d_in[0];
  const int*   ei  = (const int*)  d_in[1];
  const float* ew  = (const float*)d_in[2];
  const float* W1  = (const float*)d_in[3];
  const float* a1s = (const float*)d_in[4];
  const float* a1d = (const float*)d_in[5];
  const float* b1  = (const float*)d_in[6];
  const float* lw1 = (const float*)d_in[7];
  const float* lb1 = (const float*)d_in[8];
  const float* W2  = (const float*)d_in[9];
  const float* a2s = (const float*)d_in[10];
  const float* a2d = (const float*)d_in[11];
  const float* b2  = (const float*)d_in[12];
  const float* lw2 = (const float*)d_in[13];
  const float* lb2 = (const float*)d_in[14];
  const float* W3  = (const float*)d_in[15];
  const float* a3s = (const float*)d_in[16];
  const float* a3d = (const float*)d_in[17];
  const float* b3  = (const float*)d_in[18];
  const float* lw3 = (const float*)d_in[19];
  const float* lb3 = (const float*)d_in[20];

  char* ws = (char*)d_ws;
  size_t off = 0;
  auto alloc = [&](size_t bytes) -> void* {
    void* p = ws + off;
    off = (off + bytes + 255) & ~(size_t)255;
    return p;
  };
  ushort* Gatt = (ushort*)alloc((size_t)Mpad*F1*2);  // layer3: [Mpad][60]
  ushort* Skip = (ushort*)alloc((size_t)Mpad*F1*2);  // layer3: [Mpad][10]
  ushort* H    = (ushort*)alloc((size_t)Mpad*F1*2);
  ushort* xb   = (ushort*)alloc((size_t)Mpad*F*2);
  ushort* BT   = (ushort*)alloc((size_t)NT*1024*2);
  float*  als  = (float*) alloc((size_t)N*6*4);
  float*  ald  = (float*) alloc((size_t)N*6*4);
  int*    counts = (int*)alloc((size_t)N*4);
  int*    cursor = (int*)alloc((size_t)N*4);
  int*    indptr = (int*)alloc((size_t)(N+1)*4);
  int*    csrc   = (int*)alloc((size_t)ET*4);
  float*  cew    = (float*)alloc((size_t)ET*4);
  if (off > ws_size) return;

  hipMemsetAsync(counts, 0, (size_t)N*4, stream);
  hipMemsetAsync(cursor, 0, (size_t)N*4, stream);
  hipMemsetAsync(xb + (size_t)N*F,  0, (size_t)(Mpad-N)*F*2,  stream);
  hipMemsetAsync(H  + (size_t)N*F1, 0, (size_t)(Mpad-N)*F1*2, stream);

  k_count<<<(ET+255)/256, 256, 0, stream>>>(ei, counts, E, ET);
  k_scan<<<1, 1024, 0, stream>>>(counts, indptr, N);
  k_fill<<<(ET+255)/256, 256, 0, stream>>>(ei, ew, indptr, cursor, csrc, cew, E, ET);
  k_f2b<<<(N*F/8+255)/256, 256, 0, stream>>>(x, xb, N*F/8);

  // ---- layer 1 ----
  hipMemsetAsync(als, 0, (size_t)N*4*4, stream);
  hipMemsetAsync(ald, 0, (size_t)N*4*4, stream);
  k_packB<<<dim3((F+31)/32, NT/32), 256, 0, stream>>>(W1, lw1, BT, F, 1024, 1024, NT);
  k_gemm<<<dim3(NWG), 256, 0, stream>>>(xb, BT, Gatt, Skip, als, ald, a1s, a1d,
                                        F, 1024, 1024, NT/128, NWG/8, N);
  k_agg<<<N, 256, 0, stream>>>(Gatt, Skip, als, ald, b1, lb1, indptr, csrc, cew, H, N);

  // ---- layer 2 ----
  hipMemsetAsync(als, 0, (size_t)N*4*4, stream);
  hipMemsetAsync(ald, 0, (size_t)N*4*4, stream);
  k_packB<<<dim3(F1/32, NT/32), 256, 0, stream>>>(W2, lw2, BT, F1, 1024, 1024, NT);
  k_gemm<<<dim3(NWG), 256, 0, stream>>>(H, BT, Gatt, Skip, als, ald, a2s, a2d,
                                        F1, 1024, 1024, NT/128, NWG/8, N);
  k_agg<<<N, 256, 0, stream>>>(Gatt, Skip, als, ald, b2, lb2, indptr, csrc, cew, H, N);

  // ---- layer 3 ----
  k_packB<<<dim3(F1/32, 128/32), 256, 0, stream>>>(W3, lw3, BT, F1, 60, 10, 128);
  k_gemm<<<dim3(Mpad/128), 256, 0, stream>>>(H, BT, Gatt, Skip, nullptr, nullptr, a3s, a3d,
                                             F1, 60, 10, 1, 0, N);
  k_al3<<<(N+255)/256, 256, 0, stream>>>(Gatt, a3s, a3d, als, ald, N);
  k_agg3<<<N, 64, 0, stream>>>(Gatt, Skip, als, ald, b3, lb3, indptr, csrc, cew,
                               (float*)d_out, N);
}

// Round 5
// 501.330 us; speedup vs baseline: 1.1749x; 1.1749x over previous
//
#include <hip/hip_runtime.h>

typedef __attribute__((ext_vector_type(8))) short s16x8;
typedef __attribute__((ext_vector_type(8))) __bf16 bf16x8;
typedef __attribute__((ext_vector_type(4))) float f32x4;

__device__ inline float bf2f(ushort u){ return __uint_as_float(((unsigned)u)<<16); }
__device__ inline ushort f2bf(float f){
  unsigned u = __float_as_uint(f);
  unsigned r = (u + 0x7fffu + ((u>>16)&1u)) >> 16;
  return (ushort)r;
}

__device__ inline void gl_lds16(const ushort* g, ushort* l){
  __builtin_amdgcn_global_load_lds(
      (const __attribute__((address_space(1))) unsigned int*)g,
      (__attribute__((address_space(3))) unsigned int*)l,
      16, 0, 0);
}

// ---------------- CSR build ----------------
__global__ void k_count(const int* __restrict__ ei, int* __restrict__ counts,
                        int E, int ET){
  int e = blockIdx.x*256 + threadIdx.x;
  if (e >= ET) return;
  int dst = (e < E) ? ei[E + e] : (e - E);
  atomicAdd(&counts[dst], 1);
}

__global__ __launch_bounds__(1024) void k_scan(const int* __restrict__ cnt,
                                               int* __restrict__ indptr, int N){
  __shared__ int part[1024];
  int t = threadIdx.x;
  int per = (N + 1023) / 1024;
  int base = t * per;
  int s = 0;
  for (int i = 0; i < per; ++i){ int idx = base + i; if (idx < N) s += cnt[idx]; }
  part[t] = s; __syncthreads();
  for (int off = 1; off < 1024; off <<= 1){
    int v = (t >= off) ? part[t-off] : 0;
    __syncthreads();
    if (t >= off) part[t] += v;
    __syncthreads();
  }
  int run = (t == 0) ? 0 : part[t-1];
  for (int i = 0; i < per; ++i){
    int idx = base + i;
    if (idx < N){ indptr[idx] = run; run += cnt[idx]; }
  }
  if (t == 1023) indptr[N] = run;
}

__global__ void k_fill(const int* __restrict__ ei, const float* __restrict__ ew,
                       const int* __restrict__ indptr, int* __restrict__ cursor,
                       int* __restrict__ csrc, float* __restrict__ cew,
                       int E, int ET){
  int e = blockIdx.x*256 + threadIdx.x;
  if (e >= ET) return;
  int src, dst; float w;
  if (e < E){ src = ei[e]; dst = ei[E + e]; w = ew[e]; }
  else { src = dst = e - E; w = 1.0f; }
  int pos = indptr[dst] + atomicAdd(&cursor[dst], 1);
  csrc[pos] = src; cew[pos] = w;
}

// ---------------- conversions / packing ----------------
// converts n8valid groups of 8; zero-fills up to n8total (pad rows for GEMM)
__global__ void k_f2b(const float* __restrict__ x, ushort* __restrict__ xb,
                      int n8valid, int n8total){
  int i = blockIdx.x*256 + threadIdx.x;
  if (i >= n8total) return;
  s16x8 o = {0,0,0,0,0,0,0,0};
  if (i < n8valid){
    const float4* p = (const float4*)x + (size_t)i*2;
    float4 a = p[0], b = p[1];
    o[0]=(short)f2bf(a.x); o[1]=(short)f2bf(a.y); o[2]=(short)f2bf(a.z); o[3]=(short)f2bf(a.w);
    o[4]=(short)f2bf(b.x); o[5]=(short)f2bf(b.y); o[6]=(short)f2bf(b.z); o[7]=(short)f2bf(b.w);
  }
  *((s16x8*)xb + i) = o;
}

// BT[n][k] = concat(W, LW)^T, zero-padded to Npad rows. Coalesced via LDS tile.
__global__ __launch_bounds__(256) void k_packB(
    const float* __restrict__ W, const float* __restrict__ LW,
    ushort* __restrict__ BT, int K, int NW, int NL, int Npad)
{
  __shared__ float tile[32][33];
  int k0 = blockIdx.x*32, n0 = blockIdx.y*32;
  int c = threadIdx.x & 31, r4 = threadIdx.x >> 5;
  #pragma unroll
  for (int rr = 0; rr < 32; rr += 8){
    int k = k0 + r4 + rr, n = n0 + c;
    float v = 0.f;
    if (k < K){
      if (n < NW)            v = W[(size_t)k*NW + n];
      else if (n < NW + NL)  v = LW[(size_t)k*NL + (n - NW)];
    }
    tile[r4+rr][c] = v;
  }
  __syncthreads();
  #pragma unroll
  for (int rr = 0; rr < 32; rr += 8){
    int n = n0 + r4 + rr, k = k0 + c;
    if (n < Npad && k < K) BT[(size_t)n*K + k] = f2bf(tile[c][r4+rr]);
  }
}

// ---------------- MFMA GEMM: BK=64, XOR-swizzled LDS, XCD-chunked grid ----------------
// C[Mpad][*] = A[Mpad][K] * BT^T ; cols <GW -> Gatt bf16, [GW,GW+SW) -> Skip bf16
__global__ __launch_bounds__(256) void k_gemm(
    const ushort* __restrict__ A, const ushort* __restrict__ BT,
    ushort* __restrict__ Gatt, ushort* __restrict__ Skip,
    int K, int GW, int SW, int NCB, int CPX)
{
  __shared__ ushort As[128*64];
  __shared__ ushort Bs[128*64];
  const int bid = blockIdx.x;
  const int lb = CPX ? ((bid & 7)*CPX + (bid >> 3)) : bid;  // XCD-chunked, bijective
  const size_t row0 = (size_t)(lb / NCB) * 128;
  const size_t col0 = (size_t)(lb % NCB) * 128;             // col fastest: A-panel L2 reuse
  const int t = threadIdx.x;
  const int l = t & 63, w = t >> 6;
  const int wr = w >> 1, wc = w & 1;
  const int sr = l >> 3;
  const int sk = ((l & 7) ^ sr) << 3;       // pre-swizzled source k-offset
  const ushort* gA = A  + (row0 + w*8 + sr)*(size_t)K + sk;
  const ushort* gB = BT + (col0 + w*8 + sr)*(size_t)K + sk;
  ushort* lA = As + w*512;                  // wave-uniform linear dest
  ushort* lB = Bs + w*512;
  const int rf = l & 15;
  const int g4 = l >> 4;
  f32x4 acc[4][4] = {};

  for (int k0 = 0; k0 < K; k0 += 64){
    #pragma unroll
    for (int i = 0; i < 4; ++i){
      gl_lds16(gA + k0 + (size_t)(i*32)*K, lA + i*2048);
      gl_lds16(gB + k0 + (size_t)(i*32)*K, lB + i*2048);
    }
    __syncthreads();
    #pragma unroll
    for (int kk = 0; kk < 2; ++kk){
      const int koff = ((((kk<<2) | g4) ^ (rf & 7)) << 3);  // swizzled read
      bf16x8 af[4], bfr[4];
      #pragma unroll
      for (int i = 0; i < 4; ++i)
        af[i] = __builtin_bit_cast(bf16x8, *(const s16x8*)(As + (wr*64 + i*16 + rf)*64 + koff));
      #pragma unroll
      for (int j = 0; j < 4; ++j)
        bfr[j] = __builtin_bit_cast(bf16x8, *(const s16x8*)(Bs + (wc*64 + j*16 + rf)*64 + koff));
      #pragma unroll
      for (int i = 0; i < 4; ++i)
        #pragma unroll
        for (int j = 0; j < 4; ++j)
          acc[i][j] = __builtin_amdgcn_mfma_f32_16x16x32_bf16(af[i], bfr[j], acc[i][j], 0, 0, 0);
    }
    __syncthreads();
  }

  #pragma unroll
  for (int i = 0; i < 4; ++i){
    #pragma unroll
    for (int j = 0; j < 4; ++j){
      int gc = (int)col0 + wc*64 + j*16 + rf;
      #pragma unroll
      for (int r = 0; r < 4; ++r){
        size_t gr = row0 + wr*64 + i*16 + (g4<<2) + r;
        float v = acc[i][j][r];
        if (gc < GW)            Gatt[gr*GW + gc] = f2bf(v);
        else if (gc < GW + SW)  Skip[gr*SW + (gc - GW)] = f2bf(v);
      }
    }
  }
}

// ---------------- attention logits (layers 1-2: H=4, C=256) ----------------
__global__ __launch_bounds__(256) void k_al(const ushort* __restrict__ Gatt,
    const float* __restrict__ a_s, const float* __restrict__ a_d,
    float* __restrict__ als, float* __restrict__ ald, int N){
  int gw = (blockIdx.x*blockDim.x + threadIdx.x) >> 6;
  int l = threadIdx.x & 63;
  if (gw >= N) return;
  const ushort* row = Gatt + (size_t)gw*1024;
  int c0 = l*16;
  s16x8 v0 = *(const s16x8*)(row + c0);
  s16x8 v1 = *(const s16x8*)(row + c0 + 8);
  float ps = 0.f, pd = 0.f;
  #pragma unroll
  for (int q = 0; q < 8; ++q){
    float f0 = bf2f((ushort)v0[q]), f1 = bf2f((ushort)v1[q]);
    ps += f0*a_s[c0+q] + f1*a_s[c0+8+q];
    pd += f0*a_d[c0+q] + f1*a_d[c0+8+q];
  }
  #pragma unroll
  for (int off = 8; off; off >>= 1){
    ps += __shfl_down(ps, off);
    pd += __shfl_down(pd, off);
  }
  if ((l & 15) == 0){
    als[(size_t)gw*4 + (l>>4)] = ps;
    ald[(size_t)gw*4 + (l>>4)] = pd;
  }
}

// ---------------- softmax + aggregate + bias + skip + ELU (layers 1-2) ----------------
// grid = Mpad blocks: blocks n>=N just zero their Hout row (GEMM pad rows).
__global__ __launch_bounds__(256) void k_agg(
    const ushort* __restrict__ Gatt,   // [Mpad][1024] bf16
    const ushort* __restrict__ Skip,   // [Mpad][1024] bf16
    const float*  __restrict__ als,    // [N][4]
    const float*  __restrict__ ald,    // [N][4]
    const float*  __restrict__ bias,   // [1024]
    const float*  __restrict__ lbias,  // [1024]
    const int*    __restrict__ indptr,
    const int*    __restrict__ csrc,
    const float*  __restrict__ cew,
    ushort* __restrict__ Hout,         // [Mpad][1024] bf16
    int N)
{
  const int n = blockIdx.x;
  const int t = threadIdx.x;
  if (n >= N){
    ushort4 z = {0,0,0,0};
    *(ushort4*)(Hout + (size_t)n*1024 + t*4) = z;
    return;
  }
  const int l = t & 63, w = t >> 6;
  const int beg = indptr[n];
  const int deg = indptr[n+1] - beg;
  __shared__ float s_ald[4], s_m[4], s_den[4];
  __shared__ int   s_src[64];
  __shared__ float s_w[64][4];
  __shared__ float s_part[3][64][16];
  if (t < 4) s_ald[t] = ald[(size_t)n*4 + t];
  __syncthreads();
  const bool fast = (deg <= 64);

  if (fast){
    int e2 = t >> 2, hh = t & 3;
    if (e2 < deg){
      int s = csrc[beg + e2];
      if (hh == 0) s_src[e2] = s;
      float r_ = als[(size_t)s*4 + hh] + s_ald[hh];
      s_w[e2][hh] = r_ > 0.f ? r_ : 0.2f*r_;
    }
    __syncthreads();
    float mye = (l < deg) ? s_w[l][w] : -1e30f;
    float mx = mye;
    #pragma unroll
    for (int o = 32; o; o >>= 1) mx = fmaxf(mx, __shfl_xor(mx, o));
    float ex = (l < deg) ? __expf(mye - mx) : 0.f;
    float den = ex;
    #pragma unroll
    for (int o = 32; o; o >>= 1) den += __shfl_xor(den, o);
    den += 1e-16f;
    if (l < deg) s_w[l][w] = ex / den * cew[beg + l];
    __syncthreads();
  } else {
    const float aldh = s_ald[w];
    float mx = -1e30f;
    for (int i = l; i < deg; i += 64){
      int s = csrc[beg+i];
      float e = als[(size_t)s*4 + w] + aldh;
      e = e > 0.f ? e : 0.2f*e;
      mx = fmaxf(mx, e);
    }
    #pragma unroll
    for (int off = 32; off; off >>= 1) mx = fmaxf(mx, __shfl_xor(mx, off));
    if (l == 0) s_m[w] = mx;
    __syncthreads();
    const float mh = s_m[w];
    float den = 0.f;
    for (int i = l; i < deg; i += 64){
      int s = csrc[beg+i];
      float e = als[(size_t)s*4 + w] + aldh;
      e = e > 0.f ? e : 0.2f*e;
      den += __expf(e - mh);
    }
    #pragma unroll
    for (int off = 32; off; off >>= 1) den += __shfl_xor(den, off);
    if (l == 0) s_den[w] = den + 1e-16f;
    __syncthreads();
  }

  // gather: 4 wave-groups, each every 4th edge; thread owns 16 cols
  const int h2 = l >> 4;
  const ushort* gbase = Gatt + (size_t)l*16;
  float a[16];
  #pragma unroll
  for (int q = 0; q < 16; ++q) a[q] = 0.f;
  for (int c0 = 0; c0 < deg; c0 += 64){
    int nc = min(64, deg - c0);
    if (!fast){
      int ei2 = t >> 2, hh = t & 3;
      if (ei2 < nc){
        int s = csrc[beg + c0 + ei2];
        if (hh == 0) s_src[ei2] = s;
        float e = als[(size_t)s*4 + hh] + s_ald[hh];
        e = e > 0.f ? e : 0.2f*e;
        s_w[ei2][hh] = __expf(e - s_m[hh]) / s_den[hh] * cew[beg + c0 + ei2];
      }
      __syncthreads();
    }
    for (int j = w; j < nc; j += 4){
      int s = s_src[j];
      float wg = s_w[j][h2];
      const ushort* rp = gbase + (size_t)s*1024;
      s16x8 h0 = *(const s16x8*)rp;
      s16x8 h1 = *(const s16x8*)(rp + 8);
      #pragma unroll
      for (int q = 0; q < 8; ++q) a[q] += wg * bf2f((ushort)h0[q]);
      #pragma unroll
      for (int q = 0; q < 8; ++q) a[q+8] += wg * bf2f((ushort)h1[q]);
    }
    __syncthreads();
  }
  if (w){
    #pragma unroll
    for (int q = 0; q < 16; ++q) s_part[w-1][l][q] = a[q];
  }
  __syncthreads();
  if (w == 0){
    #pragma unroll
    for (int q = 0; q < 16; ++q) a[q] += s_part[0][l][q] + s_part[1][l][q] + s_part[2][l][q];
    const int col = l*16;
    s16x8 sk0 = *(const s16x8*)(Skip + (size_t)n*1024 + col);
    s16x8 sk1 = *(const s16x8*)(Skip + (size_t)n*1024 + col + 8);
    s16x8 ov0, ov1;
    #pragma unroll
    for (int q = 0; q < 8; ++q){
      float v = a[q] + bias[col+q] + lbias[col+q] + bf2f((ushort)sk0[q]);
      v = v > 0.f ? v : __expf(v) - 1.f;
      ov0[q] = (short)f2bf(v);
      float v2 = a[q+8] + bias[col+8+q] + lbias[col+8+q] + bf2f((ushort)sk1[q]);
      v2 = v2 > 0.f ? v2 : __expf(v2) - 1.f;
      ov1[q] = (short)f2bf(v2);
    }
    *(s16x8*)(Hout + (size_t)n*1024 + col)     = ov0;
    *(s16x8*)(Hout + (size_t)n*1024 + col + 8) = ov1;
  }
}

// ---------------- layer 3: logits (H=6, C=10) ----------------
__global__ void k_al3(const ushort* __restrict__ G3, const float* __restrict__ a_s,
                      const float* __restrict__ a_d,
                      float* __restrict__ als, float* __restrict__ ald, int N){
  int n = blockIdx.x*256 + threadIdx.x;
  if (n >= N) return;
  const ushort* row = G3 + (size_t)n*60;
  #pragma unroll
  for (int h = 0; h < 6; ++h){
    float ps = 0.f, pd = 0.f;
    #pragma unroll
    for (int c = 0; c < 10; ++c){
      float v = bf2f(row[h*10 + c]);
      ps += v * a_s[h*10 + c];
      pd += v * a_d[h*10 + c];
    }
    als[(size_t)n*6 + h] = ps;
    ald[(size_t)n*6 + h] = pd;
  }
}

// ---------------- layer 3: edge-parallel online softmax + aggregate + mean ----------------
__global__ __launch_bounds__(64) void k_agg3(
    const ushort* __restrict__ G3,     // [Mpad][60] bf16
    const ushort* __restrict__ Skip3,  // [Mpad][10] bf16
    const float*  __restrict__ als,    // [N][6]
    const float*  __restrict__ ald,    // [N][6]
    const float*  __restrict__ b3,     // [10]
    const float*  __restrict__ lb3,    // [10]
    const int*    __restrict__ indptr,
    const int*    __restrict__ csrc,
    const float*  __restrict__ cew,
    float* __restrict__ out, int N)
{
  const int n = blockIdx.x;
  const int l = threadIdx.x;
  const int beg = indptr[n], deg = indptr[n+1] - beg;
  __shared__ float s_aldh[6];
  __shared__ int   s_src[64];
  __shared__ float s_wgt[64][6];
  __shared__ float s_o[6][10];
  if (l < 6) s_aldh[l] = ald[(size_t)n*6 + l];
  __syncthreads();
  float m0=-1e30f,m1=-1e30f,m2=-1e30f,m3=-1e30f,m4=-1e30f,m5=-1e30f;
  float d0=0.f,d1=0.f,d2=0.f,d3=0.f,d4=0.f,d5=0.f;
  for (int c0 = 0; c0 < deg; c0 += 64){
    int nc = min(64, deg - c0);
    bool act = l < nc;
    int s = act ? csrc[beg + c0 + l] : 0;
#define HP(hh, mm, dd) { \
    float e = -1e30f; \
    if (act){ float r_ = als[(size_t)s*6 + hh] + s_aldh[hh]; e = r_ > 0.f ? r_ : 0.2f*r_; } \
    float cm = e; \
    for (int o_ = 32; o_; o_ >>= 1) cm = fmaxf(cm, __shfl_xor(cm, o_)); \
    float nm = fmaxf(mm, cm); \
    float ex = act ? __expf(e - nm) : 0.f; \
    for (int o_ = 32; o_; o_ >>= 1) ex += __shfl_xor(ex, o_); \
    dd = dd * __expf(mm - nm) + ex; mm = nm; }
    HP(0,m0,d0) HP(1,m1,d1) HP(2,m2,d2) HP(3,m3,d3) HP(4,m4,d4) HP(5,m5,d5)
#undef HP
  }
  const int h = l / 10, c = l % 10;     // valid for l<60
  float o = 0.f;
  for (int c0 = 0; c0 < deg; c0 += 64){
    int nc = min(64, deg - c0);
    if (l < nc){
      int s = csrc[beg + c0 + l];
      s_src[l] = s;
      float w_ = cew[beg + c0 + l];
#define WP(hh, mm, dd) { \
      float r_ = als[(size_t)s*6 + hh] + s_aldh[hh]; \
      float e = r_ > 0.f ? r_ : 0.2f*r_; \
      s_wgt[l][hh] = __expf(e - mm) / (dd + 1e-16f) * w_; }
      WP(0,m0,d0) WP(1,m1,d1) WP(2,m2,d2) WP(3,m3,d3) WP(4,m4,d4) WP(5,m5,d5)
#undef WP
    }
    __syncthreads();
    if (l < 60){
      for (int i = 0; i < nc; ++i)
        o += s_wgt[i][h] * bf2f(G3[(size_t)s_src[i]*60 + l]);
    }
    __syncthreads();
  }
  if (l < 60) s_o[h][c] = o;
  __syncthreads();
  if (l < 10){
    float v = (s_o[0][l]+s_o[1][l]+s_o[2][l]+s_o[3][l]+s_o[4][l]+s_o[5][l]) * (1.0f/6.0f);
    v += b3[l] + lb3[l] + bf2f(Skip3[(size_t)n*10 + l]);
    out[(size_t)n*10 + l] = v;
  }
}

// ---------------- host ----------------
extern "C" void kernel_launch(void* const* d_in, const int* in_sizes, int n_in,
                              void* d_out, int out_size, void* d_ws, size_t ws_size,
                              hipStream_t stream)
{
  const int N = 20000, F = 128, E = 320000, ET = E + N;
  const int Mpad = 20096;            // 157 * 128
  const int F1 = 1024, NT = 2048;
  const int NWG = (Mpad/128)*(NT/128);   // 2512, % 8 == 0

  const float* x   = (const float*)d_in[0];
  const int*   ei  = (const int*)  d_in[1];
  const float* ew  = (const float*)d_in[2];
  const float* W1  = (const float*)d_in[3];
  const float* a1s = (const float*)d_in[4];
  const float* a1d = (const float*)d_in[5];
  const float* b1  = (const float*)d_in[6];
  const float* lw1 = (const float*)d_in[7];
  const float* lb1 = (const float*)d_in[8];
  const float* W2  = (const float*)d_in[9];
  const float* a2s = (const float*)d_in[10];
  const float* a2d = (const float*)d_in[11];
  const float* b2  = (const float*)d_in[12];
  const float* lw2 = (const float*)d_in[13];
  const float* lb2 = (const float*)d_in[14];
  const float* W3  = (const float*)d_in[15];
  const float* a3s = (const float*)d_in[16];
  const float* a3d = (const float*)d_in[17];
  const float* b3  = (const float*)d_in[18];
  const float* lw3 = (const float*)d_in[19];
  const float* lb3 = (const float*)d_in[20];

  char* ws = (char*)d_ws;
  size_t off = 0;
  auto alloc = [&](size_t bytes) -> void* {
    void* p = ws + off;
    off = (off + bytes + 255) & ~(size_t)255;
    return p;
  };
  ushort* Gatt = (ushort*)alloc((size_t)Mpad*F1*2);  // layer3: [Mpad][60]
  ushort* Skip = (ushort*)alloc((size_t)Mpad*F1*2);  // layer3: [Mpad][10]
  ushort* H    = (ushort*)alloc((size_t)Mpad*F1*2);
  ushort* xb   = (ushort*)alloc((size_t)Mpad*F*2);
  ushort* BT   = (ushort*)alloc((size_t)NT*1024*2);
  float*  als  = (float*) alloc((size_t)N*6*4);
  float*  ald  = (float*) alloc((size_t)N*6*4);
  int*    counts = (int*)alloc((size_t)2*N*4);   // counts + cursor, one memset
  int*    cursor = counts + N;
  int*    indptr = (int*)alloc((size_t)(N+1)*4);
  int*    csrc   = (int*)alloc((size_t)ET*4);
  float*  cew    = (float*)alloc((size_t)ET*4);
  if (off > ws_size) return;

  hipMemsetAsync(counts, 0, (size_t)2*N*4, stream);
  k_count<<<(ET+255)/256, 256, 0, stream>>>(ei, counts, E, ET);
  k_scan<<<1, 1024, 0, stream>>>(counts, indptr, N);
  k_fill<<<(ET+255)/256, 256, 0, stream>>>(ei, ew, indptr, cursor, csrc, cew, E, ET);
  k_f2b<<<(Mpad*F/8+255)/256, 256, 0, stream>>>(x, xb, N*F/8, Mpad*F/8);

  // ---- layer 1 ----
  k_packB<<<dim3((F+31)/32, NT/32), 256, 0, stream>>>(W1, lw1, BT, F, 1024, 1024, NT);
  k_gemm<<<dim3(NWG), 256, 0, stream>>>(xb, BT, Gatt, Skip, F, 1024, 1024, NT/128, NWG/8);
  k_al<<<(N+3)/4, 256, 0, stream>>>(Gatt, a1s, a1d, als, ald, N);
  k_agg<<<Mpad, 256, 0, stream>>>(Gatt, Skip, als, ald, b1, lb1, indptr, csrc, cew, H, N);

  // ---- layer 2 ----
  k_packB<<<dim3(F1/32, NT/32), 256, 0, stream>>>(W2, lw2, BT, F1, 1024, 1024, NT);
  k_gemm<<<dim3(NWG), 256, 0, stream>>>(H, BT, Gatt, Skip, F1, 1024, 1024, NT/128, NWG/8);
  k_al<<<(N+3)/4, 256, 0, stream>>>(Gatt, a2s, a2d, als, ald, N);
  k_agg<<<Mpad, 256, 0, stream>>>(Gatt, Skip, als, ald, b2, lb2, indptr, csrc, cew, H, N);

  // ---- layer 3 ----
  k_packB<<<dim3(F1/32, 128/32), 256, 0, stream>>>(W3, lw3, BT, F1, 60, 10, 128);
  k_gemm<<<dim3(Mpad/128), 256, 0, stream>>>(H, BT, Gatt, Skip, F1, 60, 10, 1, 0);
  k_al3<<<(N+255)/256, 256, 0, stream>>>(Gatt, a3s, a3d, als, ald, N);
  k_agg3<<<N, 64, 0, stream>>>(Gatt, Skip, als, ald, b3, lb3, indptr, csrc, cew,
                               (float*)d_out, N);
}